// Round 3
// baseline (6568.634 us; speedup 1.0000x reference)
//
#include <hip/hip_runtime.h>
#include <math.h>

// Problem constants (fixed by reference)
#define Bsz   64
#define NPG   160
#define PP    16
#define HH    300
#define DEGc  16
#define NI    5
#define NOUT  2000
#define NN    (Bsz*NPG)      // 10240 nodes
#define EE    (NN*DEGc)      // 163840 edges
#define DD    (PP+1)         // 17
#define NSTEP (NI-1)         // 4
#define KN    (PP*HH)        // 4800 (node GEMM K)
#define H2    (2*HH)         // 600
#define TK    16             // K tile
#define LDP   68             // padded LDS row (16B-aligned, conflict-free)

__device__ __forceinline__ float eluf(float x){ return x > 0.f ? x : expm1f(x); }

// ---------------------------------------------------------------------------
// sims[b,i,d] = softmax_d( instructions[b,i,:] . property_embeddings[d,:] )
// ---------------------------------------------------------------------------
__global__ __launch_bounds__(64) void k_sims(const float* __restrict__ instr,
                                             const float* __restrict__ pe,
                                             float* __restrict__ sims)
{
    const int bi = blockIdx.x;          // b*NI + i
    const int d  = threadIdx.x;
    __shared__ float lg[DD];
    if (d < DD){
        float acc = 0.f;
        const float* ipw = instr + (size_t)bi*HH;
        const float* pp  = pe + (size_t)d*HH;
        for (int h=0; h<HH; ++h) acc = fmaf(ipw[h], pp[h], acc);
        lg[d] = acc;
    }
    __syncthreads();
    if (d == 0){
        float m = -1e30f;
        for (int j=0;j<DD;++j) m = fmaxf(m, lg[j]);
        float ssum = 0.f;
        for (int j=0;j<DD;++j){ lg[j] = expf(lg[j]-m); ssum += lg[j]; }
        float inv = 1.f/ssum;
        for (int j=0;j<DD;++j) sims[(size_t)bi*DD + j] = lg[j]*inv;
    }
}

// ---------------------------------------------------------------------------
// Node GEMM, ALL 4 STEPS FUSED.
// NL[s,n] = sum_k elu( sum_{ph} na[n,ph] * (psim_s[p]*instr_s[h]) * W[ph,k] )
//           * w_node[k]
// Step-dependent gate is a diagonal scale on the K axis -> per-tile Sc[16][4];
// A-tile (na) and W-tile loaded ONCE for all 4 steps.
// Tile: 64 rows x 64 cols, K=4800.  grid(ct=5, rt=3, b=64).
// ---------------------------------------------------------------------------
__global__ __launch_bounds__(256) void k_node(
    const float* __restrict__ na, const float* __restrict__ wp,
    const float* __restrict__ instr, const float* __restrict__ sims,
    const float* __restrict__ w_node, float* __restrict__ NL)
{
    const int ct = blockIdx.x, rt = blockIdx.y, b = blockIdx.z;
    const int tid = threadIdx.x;
    const int tx = tid & 15, ty = tid >> 4;
    const int h0 = ct*64, r0 = rt*64;

    __shared__ float At[TK][LDP];     // [k][row], raw na
    __shared__ float Wt[TK][LDP];     // [k][col]
    __shared__ float Sc[TK][4];       // per-k gate, per step
    __shared__ float rowsum[NSTEP][64];

    const float* ipw_b = instr + (size_t)b*NI*HH;   // + s*HH
    const float* sp_b  = sims  + (size_t)b*NI*DD;   // + s*DD

    float acc[NSTEP][4][4] = {{{0.f}}};

    const int lr = tid >> 2;            // 0..63 (row)
    const int lk = (tid & 3) * 4;       // 0,4,8,12
    const int wk = tid >> 4;            // 0..15
    const int wc = (tid & 15) * 4;      // 0..60

    const bool rok = (r0 + lr) < NPG;
    const float* arow = na + (size_t)(b*NPG + r0 + lr)*KN;

    for (int k0 = 0; k0 < KN; k0 += TK){
        { // A tile: raw (no gating), float4 never straddles p (300 % 4 == 0)
            float4 v = make_float4(0.f,0.f,0.f,0.f);
            if (rok) v = *(const float4*)(arow + k0 + lk);
            At[lk+0][lr]=v.x; At[lk+1][lr]=v.y; At[lk+2][lr]=v.z; At[lk+3][lr]=v.w;
        }
        { // W tile
            const float* wrow = wp + (size_t)(k0 + wk)*HH + h0 + wc;
            float4 v = make_float4(0.f,0.f,0.f,0.f);
            if (h0 + wc + 3 < HH) v = *(const float4*)wrow;
            else {
                if (h0+wc+0 < HH) v.x = wrow[0];
                if (h0+wc+1 < HH) v.y = wrow[1];
                if (h0+wc+2 < HH) v.z = wrow[2];
                if (h0+wc+3 < HH) v.w = wrow[3];
            }
            *(float4*)&Wt[wk][wc] = v;
        }
        if (tid < TK*NSTEP){ // per-k step gates
            const int kk = tid >> 2, s = tid & 3;
            const int k = k0 + kk;
            const int p = k / HH;
            const int h = k - p*HH;
            Sc[kk][s] = sp_b[s*DD + p] * ipw_b[s*HH + h];
        }
        __syncthreads();
        #pragma unroll
        for (int k=0; k<TK; ++k){
            const float4 a  = *(const float4*)&At[k][ty*4];
            const float4 w  = *(const float4*)&Wt[k][tx*4];
            const float4 sc = *(const float4*)&Sc[k][0];
            const float av[4]={a.x,a.y,a.z,a.w}, wv[4]={w.x,w.y,w.z,w.w};
            const float scv[4]={sc.x,sc.y,sc.z,sc.w};
            #pragma unroll
            for (int s=0;s<NSTEP;++s){
                float ws0=wv[0]*scv[s], ws1=wv[1]*scv[s], ws2=wv[2]*scv[s], ws3=wv[3]*scv[s];
                #pragma unroll
                for (int i=0;i<4;++i){
                    acc[s][i][0] = fmaf(av[i], ws0, acc[s][i][0]);
                    acc[s][i][1] = fmaf(av[i], ws1, acc[s][i][1]);
                    acc[s][i][2] = fmaf(av[i], ws2, acc[s][i][2]);
                    acc[s][i][3] = fmaf(av[i], ws3, acc[s][i][3]);
                }
            }
        }
        __syncthreads();
    }

    // epilogue: elu + dot w_node over this col-tile, reduce across tx (16 lanes)
    float wn[4];
    #pragma unroll
    for (int j=0;j<4;++j){
        const int hc = h0 + tx*4 + j;
        wn[j] = (hc < HH) ? w_node[hc] : 0.f;
    }
    #pragma unroll
    for (int s=0;s<NSTEP;++s)
        #pragma unroll
        for (int i=0;i<4;++i){
            float rs = 0.f;
            #pragma unroll
            for (int j=0;j<4;++j) rs += eluf(acc[s][i][j]) * wn[j];
            rs += __shfl_xor(rs, 1, 16);
            rs += __shfl_xor(rs, 2, 16);
            rs += __shfl_xor(rs, 4, 16);
            rs += __shfl_xor(rs, 8, 16);
            if (tx == 0) rowsum[s][ty*4+i] = rs;
        }
    __syncthreads();
    {
        const int s = tid >> 6, row = tid & 63;
        if (r0 + row < NPG)
            atomicAdd(&NL[(size_t)s*NN + b*NPG + r0 + row], rowsum[s][row]);
    }
}

// ---------------------------------------------------------------------------
// Edge GEMM, ALL 4 STEPS FUSED (gate = instr_s[k] on the K axis).
// ET[s,e] = sum_h elu( sum_k ea[e,k]*instr_s[k]*W_edge[k,h] ) * w_rel[h]
// grid(ct=5, rt=40, b=64).
// ---------------------------------------------------------------------------
__global__ __launch_bounds__(256) void k_edge(
    const float* __restrict__ ea, const float* __restrict__ we,
    const float* __restrict__ instr, const float* __restrict__ w_rel,
    float* __restrict__ ET)
{
    const int ct = blockIdx.x, rt = blockIdx.y, b = blockIdx.z;
    const int tid = threadIdx.x;
    const int tx = tid & 15, ty = tid >> 4;
    const int h0 = ct*64;
    const int e0 = b*NPG*DEGc + rt*64;

    __shared__ float At[TK][LDP];
    __shared__ float Wt[TK][LDP];
    __shared__ float Sc[TK][4];
    __shared__ float rowsum[NSTEP][64];

    const float* ipw_b = instr + (size_t)b*NI*HH;

    float acc[NSTEP][4][4] = {{{0.f}}};

    const int lr = tid >> 2;
    const int lk = (tid & 3) * 4;
    const int wk = tid >> 4;
    const int wc = (tid & 15) * 4;

    const float* erow = ea + (size_t)(e0 + lr)*HH;

    for (int k0 = 0; k0 < HH; k0 += TK){      // 19 tiles, last partial
        {
            const int k = k0 + lk;
            float4 v = make_float4(0.f,0.f,0.f,0.f);
            if (k + 3 < HH) v = *(const float4*)(erow + k);
            else {
                if (k+0 < HH) v.x = erow[k+0];
                if (k+1 < HH) v.y = erow[k+1];
                if (k+2 < HH) v.z = erow[k+2];
                if (k+3 < HH) v.w = erow[k+3];
            }
            At[lk+0][lr]=v.x; At[lk+1][lr]=v.y; At[lk+2][lr]=v.z; At[lk+3][lr]=v.w;
        }
        {
            const int kr = k0 + wk;
            float4 v = make_float4(0.f,0.f,0.f,0.f);
            if (kr < HH){
                const float* wrow = we + (size_t)kr*HH + h0 + wc;
                if (h0 + wc + 3 < HH) v = *(const float4*)wrow;
                else {
                    if (h0+wc+0 < HH) v.x = wrow[0];
                    if (h0+wc+1 < HH) v.y = wrow[1];
                    if (h0+wc+2 < HH) v.z = wrow[2];
                }
            }
            *(float4*)&Wt[wk][wc] = v;
        }
        if (tid < TK*NSTEP){
            const int kk = tid >> 2, s = tid & 3;
            const int k = k0 + kk;
            Sc[kk][s] = (k < HH) ? ipw_b[s*HH + k] : 0.f;
        }
        __syncthreads();
        #pragma unroll
        for (int k=0; k<TK; ++k){
            const float4 a  = *(const float4*)&At[k][ty*4];
            const float4 w  = *(const float4*)&Wt[k][tx*4];
            const float4 sc = *(const float4*)&Sc[k][0];
            const float av[4]={a.x,a.y,a.z,a.w}, wv[4]={w.x,w.y,w.z,w.w};
            const float scv[4]={sc.x,sc.y,sc.z,sc.w};
            #pragma unroll
            for (int s=0;s<NSTEP;++s){
                float ws0=wv[0]*scv[s], ws1=wv[1]*scv[s], ws2=wv[2]*scv[s], ws3=wv[3]*scv[s];
                #pragma unroll
                for (int i=0;i<4;++i){
                    acc[s][i][0] = fmaf(av[i], ws0, acc[s][i][0]);
                    acc[s][i][1] = fmaf(av[i], ws1, acc[s][i][1]);
                    acc[s][i][2] = fmaf(av[i], ws2, acc[s][i][2]);
                    acc[s][i][3] = fmaf(av[i], ws3, acc[s][i][3]);
                }
            }
        }
        __syncthreads();
    }

    float wr[4];
    #pragma unroll
    for (int j=0;j<4;++j){
        const int hc = h0 + tx*4 + j;
        wr[j] = (hc < HH) ? w_rel[hc] : 0.f;
    }
    #pragma unroll
    for (int s=0;s<NSTEP;++s)
        #pragma unroll
        for (int i=0;i<4;++i){
            float rs = 0.f;
            #pragma unroll
            for (int j=0;j<4;++j) rs += eluf(acc[s][i][j]) * wr[j];
            rs += __shfl_xor(rs, 1, 16);
            rs += __shfl_xor(rs, 2, 16);
            rs += __shfl_xor(rs, 4, 16);
            rs += __shfl_xor(rs, 8, 16);
            if (tx == 0) rowsum[s][ty*4+i] = rs;
        }
    __syncthreads();
    {
        const int s = tid >> 6, row = tid & 63;
        atomicAdd(&ET[(size_t)s*EE + e0 + row], rowsum[s][row]);
    }
}

// ---------------------------------------------------------------------------
// Sequential recurrence, one block per graph (segments are contiguous 160s).
// ---------------------------------------------------------------------------
__global__ __launch_bounds__(256) void k_seq(
    const float* __restrict__ NL, const float* __restrict__ ET,
    const float* __restrict__ sims, const float* __restrict__ npg,
    const int* __restrict__ esrc, const int* __restrict__ edst,
    float* __restrict__ dist_out)
{
    const int b = blockIdx.x;
    const int tid = threadIdx.x;
    __shared__ float dist[NPG], nds[NPG], msg[NPG];
    __shared__ float red[256];

    if (tid < NPG) dist[tid] = 1.f / npg[b];
    __syncthreads();

    for (int s=0; s<NSTEP; ++s){
        // nd_states = softmax over graph of NL
        float v = (tid < NPG) ? NL[(size_t)s*NN + b*NPG + tid] : -1e30f;
        red[tid] = v; __syncthreads();
        for (int off=128; off>0; off>>=1){ if (tid<off) red[tid]=fmaxf(red[tid],red[tid+off]); __syncthreads(); }
        const float m = red[0]; __syncthreads();
        const float e = (tid < NPG) ? expf(v - m) : 0.f;
        red[tid] = e; __syncthreads();
        for (int off=128; off>0; off>>=1){ if (tid<off) red[tid]+=red[tid+off]; __syncthreads(); }
        const float se = red[0]; __syncthreads();
        if (tid < NPG) nds[tid] = e / se;
        if (tid < NPG) msg[tid] = 0.f;
        __syncthreads();
        // msg[n] = sum_{e: dst=n} dist[src]*ET[s,e]
        const int ebase = b*NPG*DEGc;
        for (int el = tid; el < NPG*DEGc; el += 256){
            const int eg = ebase + el;
            atomicAdd(&msg[edst[eg] - b*NPG], dist[esrc[eg] - b*NPG] * ET[(size_t)s*EE + eg]);
        }
        __syncthreads();
        // nd_rel = softmax(msg)
        float mv = (tid < NPG) ? msg[tid] : -1e30f;
        red[tid] = mv; __syncthreads();
        for (int off=128; off>0; off>>=1){ if (tid<off) red[tid]=fmaxf(red[tid],red[tid+off]); __syncthreads(); }
        const float mm = red[0]; __syncthreads();
        const float e2 = (tid < NPG) ? expf(mv - mm) : 0.f;
        red[tid] = e2; __syncthreads();
        for (int off=128; off>0; off>>=1){ if (tid<off) red[tid]+=red[tid+off]; __syncthreads(); }
        const float s2 = red[0]; __syncthreads();
        const float r = sims[(size_t)(b*NI + s)*DD + (DD-1)];
        if (tid < NPG) dist[tid] = r*(e2/s2) + (1.f-r)*nds[tid];
        __syncthreads();
    }
    if (tid < NPG) dist_out[b*NPG + tid] = dist[tid];
}

// ---------------------------------------------------------------------------
// agg[b,h] = sum_{n in b} dist[n] * sum_p prop_last[b,p]*na[n,p,h]
// grid(b, 10 chunks of 16 nodes), 320 threads (h = tid < 300)
// ---------------------------------------------------------------------------
__global__ __launch_bounds__(320) void k_agg(
    const float* __restrict__ na, const float* __restrict__ sims,
    const float* __restrict__ dist, float* __restrict__ agg)
{
    const int b = blockIdx.x, chunk = blockIdx.y;
    const int tid = threadIdx.x;
    __shared__ float coef[16][PP];
    if (tid < 16*PP){
        const int nl = tid / PP, p = tid % PP;
        coef[nl][p] = dist[b*NPG + chunk*16 + nl] * sims[(size_t)(b*NI + (NI-1))*DD + p];
    }
    __syncthreads();
    if (tid < HH){
        float acc = 0.f;
        for (int nl=0; nl<16; ++nl){
            const float* base = na + (size_t)(b*NPG + chunk*16 + nl)*KN + tid;
            #pragma unroll
            for (int p=0; p<PP; ++p) acc = fmaf(coef[nl][p], base[(size_t)p*HH], acc);
        }
        atomicAdd(&agg[b*HH + tid], acc);
    }
}

// ---------------------------------------------------------------------------
// MLP
// ---------------------------------------------------------------------------
__global__ __launch_bounds__(640) void k_mlp1(
    const float* __restrict__ encq, const float* __restrict__ agg,
    const float* __restrict__ W1, const float* __restrict__ b1,
    float* __restrict__ z)
{
    const int b = blockIdx.x, tid = threadIdx.x;
    __shared__ float x[H2];
    if (tid < HH) x[tid] = encq[b*HH + tid];
    else if (tid < H2) x[tid] = agg[b*HH + (tid - HH)];
    __syncthreads();
    if (tid < H2){
        float acc = b1[tid];
        for (int k=0;k<H2;++k) acc = fmaf(x[k], W1[(size_t)k*H2 + tid], acc);
        z[b*H2 + tid] = eluf(acc);
    }
}

__global__ __launch_bounds__(256) void k_mlp2(
    const float* __restrict__ z, const float* __restrict__ W2,
    const float* __restrict__ b2, float* __restrict__ out)
{
    const int b = blockIdx.x;
    const int o = blockIdx.y*256 + threadIdx.x;
    __shared__ float zs[H2];
    for (int k=threadIdx.x; k<H2; k+=256) zs[k] = z[b*H2 + k];
    __syncthreads();
    if (o < NOUT){
        float acc = b2[o];
        for (int k=0;k<H2;++k) acc = fmaf(zs[k], W2[(size_t)k*NOUT + o], acc);
        out[(size_t)b*NOUT + o] = acc;
    }
}

// ---------------------------------------------------------------------------
extern "C" void kernel_launch(void* const* d_in, const int* in_sizes, int n_in,
                              void* d_out, int out_size, void* d_ws, size_t ws_size,
                              hipStream_t stream)
{
    const float* node_attrs  = (const float*)d_in[0];
    const float* edge_attrs  = (const float*)d_in[1];
    const float* instructions= (const float*)d_in[2];
    const float* encq        = (const float*)d_in[3];
    const float* prop_emb    = (const float*)d_in[4];
    const float* npg         = (const float*)d_in[5];
    const int*   edge_src    = (const int*)d_in[8];
    const int*   edge_dst    = (const int*)d_in[9];
    const float* W_props     = (const float*)d_in[10];
    const float* W_edge      = (const float*)d_in[11];
    const float* w_node      = (const float*)d_in[12];
    const float* w_rel       = (const float*)d_in[13];
    const float* W1          = (const float*)d_in[14];
    const float* b1          = (const float*)d_in[15];
    const float* W2          = (const float*)d_in[16];
    const float* b2          = (const float*)d_in[17];
    float* out = (float*)d_out;

    float* ws   = (float*)d_ws;
    float* sims = ws;                         // B*NI*DD   = 5440
    float* NL   = sims + Bsz*NI*DD;           // NSTEP*NN  = 40960
    float* ET   = NL   + NSTEP*NN;            // NSTEP*EE  = 655360
    float* dist = ET   + (size_t)NSTEP*EE;    // NN        = 10240
    float* agg  = dist + NN;                  // B*HH      = 19200
    float* z    = agg  + Bsz*HH;              // B*H2      = 38400
    const size_t total_f = (size_t)(Bsz*NI*DD) + NSTEP*NN + (size_t)NSTEP*EE + NN + Bsz*HH + Bsz*H2;

    // NL/ET/agg are atomically accumulated -> must be zeroed (ws is 0xAA-poisoned)
    (void)hipMemsetAsync(d_ws, 0, total_f*sizeof(float), stream);

    k_sims<<<dim3(Bsz*NI), dim3(64), 0, stream>>>(instructions, prop_emb, sims);
    k_node<<<dim3(5, 3, Bsz), dim3(256), 0, stream>>>(node_attrs, W_props, instructions, sims, w_node, NL);
    k_edge<<<dim3(5, 40, Bsz), dim3(256), 0, stream>>>(edge_attrs, W_edge, instructions, w_rel, ET);
    k_seq <<<dim3(Bsz), dim3(256), 0, stream>>>(NL, ET, sims, npg, edge_src, edge_dst, dist);
    k_agg <<<dim3(Bsz, 10), dim3(320), 0, stream>>>(node_attrs, sims, dist, agg);
    k_mlp1<<<dim3(Bsz), dim3(640), 0, stream>>>(encq, agg, W1, b1, z);
    k_mlp2<<<dim3(Bsz, 8), dim3(256), 0, stream>>>(z, W2, b2, out);
}